// Round 13
// baseline (334.317 us; speedup 1.0000x reference)
//
#include <hip/hip_runtime.h>
#include <hip/hip_bf16.h>

#define NN 100000
#define NE 1600000
#define DD 64
#define HH 128
#define NLAYERS 4
#define NGRAPH 64
#define NBUCKET 782        // ceil(NN/128) buckets of 128 dst nodes
#define CHUNKSZ 8192
#define NCHUNK 196         // ceil(NE/8192)
#define NTOT (NBUCKET * NCHUNK)   // 153,272
#define NCHN 391           // ceil(NN/256) node chunks (deg sort)
#define NBIN 64
#define NTOTD (NBIN * NCHN)       // 25,024

typedef __attribute__((ext_vector_type(8))) short bf16x8;
typedef __attribute__((ext_vector_type(4))) float f32x4;
typedef __attribute__((ext_vector_type(2))) float f32x2;

__device__ inline unsigned short bf16bits(float v) {
  return __bfloat16_as_ushort(__float2bfloat16(v));
}
__device__ inline float lo16(unsigned int u) { return __uint_as_float(u << 16); }
__device__ inline float hi16(unsigned int u) { return __uint_as_float(u & 0xFFFF0000u); }
__device__ inline float b2f(unsigned short u) { return __uint_as_float(((unsigned int)u) << 16); }
__device__ inline unsigned char f8byte(float v) {
  int pk = __builtin_amdgcn_cvt_pk_fp8_f32(fmaxf(v, 0.f), 0.f, 0, false);
  return (unsigned char)(pk & 0xFF);
}

// ---------------- CSR build ----------------

__global__ void k_hist(const int* __restrict__ dst, int* __restrict__ hist) {
  __shared__ int lh[NBUCKET];
  int t = threadIdx.x;
  int blk = blockIdx.x;
  for (int i = t; i < NBUCKET; i += 256) lh[i] = 0;
  __syncthreads();
  int cb = blk * CHUNKSZ;
  int end = min(cb + CHUNKSZ, NE);
  for (int i = cb + t; i < end; i += 256)
    atomicAdd(&lh[dst[i] >> 7], 1);
  __syncthreads();
  for (int i = t; i < NBUCKET; i += 256)
    hist[i * NCHUNK + blk] = lh[i];
}

__global__ void k_scan1(const int* __restrict__ in, int* __restrict__ out,
                        int* __restrict__ bsum, int n) {
  __shared__ int s[256];
  int t = threadIdx.x;
  int i = blockIdx.x * 256 + t;
  int v = (i < n) ? in[i] : 0;
  s[t] = v;
  __syncthreads();
  for (int off = 1; off < 256; off <<= 1) {
    int x = (t >= off) ? s[t - off] : 0;
    __syncthreads();
    s[t] += x;
    __syncthreads();
  }
  if (i < n) out[i] = s[t] - v;
  if (t == 255) bsum[blockIdx.x] = s[255];
}

__global__ void k_scan2b(int* bsum, int nb) {
  __shared__ int s[256];
  int t = threadIdx.x;
  int base = t * 5;
  int v[5];
  int sum = 0;
#pragma unroll
  for (int j = 0; j < 5; j++) {
    int i = base + j;
    v[j] = (i < nb) ? bsum[i] : 0;
    sum += v[j];
  }
  s[t] = sum;
  __syncthreads();
  for (int off = 1; off < 256; off <<= 1) {
    int x = (t >= off) ? s[t - off] : 0;
    __syncthreads();
    s[t] += x;
    __syncthreads();
  }
  int ex = s[t] - sum;
#pragma unroll
  for (int j = 0; j < 5; j++) {
    int i = base + j;
    if (i < nb) { int vv = v[j]; bsum[i] = ex; ex += vv; }
  }
}

// finalize hist offsets + extract per-bucket bases (avoids hist/csr alias race)
__global__ void k_scan3b(int* __restrict__ hist, const int* __restrict__ bsum,
                         int* __restrict__ bbase, int n) {
  int i = blockIdx.x * 256 + threadIdx.x;
  if (i < n) {
    int v = hist[i] + bsum[i >> 8];
    hist[i] = v;
    if (i % NCHUNK == 0) bbase[i / NCHUNK] = v;
  }
}

// generic finalize (no base extraction)
__global__ void k_scan3c(int* __restrict__ arr, const int* __restrict__ bsum, int n) {
  int i = blockIdx.x * 256 + threadIdx.x;
  if (i < n) arr[i] += bsum[i >> 8];
}

__global__ void k_scatter(const int* __restrict__ src, const int* __restrict__ dst,
                          const int* __restrict__ hist, unsigned int* __restrict__ tmp) {
  __shared__ int lcur[NBUCKET];
  int t = threadIdx.x;
  int blk = blockIdx.x;
  for (int i = t; i < NBUCKET; i += 256) lcur[i] = hist[i * NCHUNK + blk];
  __syncthreads();
  int cb = blk * CHUNKSZ;
  int end = min(cb + CHUNKSZ, NE);
  for (int i = cb + t; i < end; i += 256) {
    int d = dst[i];
    int pos = atomicAdd(&lcur[d >> 7], 1);
    tmp[pos] = ((unsigned int)(d & 127) << 20) | (unsigned int)src[i];
  }
}

// per-bucket: derive per-node offs/cnt (LDS count+scan), then place edges
__global__ void k_fillB2(const unsigned int* __restrict__ tmp,
                         const int* __restrict__ bbase,
                         int* __restrict__ csr, int* __restrict__ offs,
                         int* __restrict__ cnt) {
  __shared__ int lcnt[128], lex[128], lcur[128];
  int b = blockIdx.x;
  int t = threadIdx.x;
  int base = bbase[b];
  int end = (b == NBUCKET - 1) ? NE : bbase[b + 1];
  if (t < 128) lcnt[t] = 0;
  __syncthreads();
  for (int i = base + t; i < end; i += 256)
    atomicAdd(&lcnt[tmp[i] >> 20], 1);
  __syncthreads();
  int v = (t < 128) ? lcnt[t] : 0;
  if (t < 128) lex[t] = v;
  __syncthreads();
  for (int off = 1; off < 128; off <<= 1) {
    int x = (t >= off && t < 128) ? lex[t - off] : 0;
    __syncthreads();
    if (t < 128) lex[t] += x;
    __syncthreads();
  }
  if (t < 128) {
    int ex = lex[t] - v;
    lcur[t] = ex;
    int node = (b << 7) + t;
    if (node < NN) { offs[node] = base + ex; cnt[node] = v; }
  }
  __syncthreads();
  for (int i = base + t; i < end; i += 256) {
    unsigned int u = tmp[i];
    int dl = u >> 20;
    int pos = atomicAdd(&lcur[dl], 1);
    csr[base + pos] = u & 0xFFFFF;
  }
}

// ---------------- degree sort: perm = nodes sorted by min(deg,63) ----------------
__global__ void k_dhist(const int* __restrict__ cnt, int* __restrict__ dh) {
  __shared__ int lh[NBIN];
  int t = threadIdx.x, blk = blockIdx.x;
  if (t < NBIN) lh[t] = 0;
  __syncthreads();
  int node = blk * 256 + t;
  if (node < NN) atomicAdd(&lh[min(cnt[node], NBIN - 1)], 1);
  __syncthreads();
  if (t < NBIN) dh[t * NCHN + blk] = lh[t];
}

__global__ void k_dscatter(const int* __restrict__ cnt, const int* __restrict__ dh,
                           int* __restrict__ perm) {
  __shared__ int lcur[NBIN];
  int t = threadIdx.x, blk = blockIdx.x;
  if (t < NBIN) lcur[t] = dh[t * NCHN + blk];
  __syncthreads();
  int node = blk * 256 + t;
  if (node < NN) {
    int pos = atomicAdd(&lcur[min(cnt[node], NBIN - 1)], 1);
    perm[pos] = node;
  }
}

// ---------------- weight prep: bf16 transposed copies ----------------
__global__ void k_prep(const float* __restrict__ W1, const float* __restrict__ W2,
                       const float* __restrict__ W_in,
                       unsigned short* __restrict__ W1t, unsigned short* __restrict__ W2t,
                       unsigned short* __restrict__ Wint) {
  int bidx = blockIdx.x;
  int t = threadIdx.x;
  if (bidx == 2 * NLAYERS) {
    for (int i = t; i < 4096; i += 256) {
      int c = i >> 6, k = i & 63;
      Wint[i] = bf16bits(W_in[k * 64 + c]);
    }
    return;
  }
  int l = bidx >> 1;
  int m = bidx & 1;
  if (m == 0) {
    const float* src = W1 + (size_t)l * 8192;
    unsigned short* dstp = W1t + (size_t)l * 8192;
    for (int i = t; i < 8192; i += 256) {
      int c = i >> 6, k = i & 63;
      dstp[i] = bf16bits(src[k * 128 + c]);
    }
  } else {
    const float* src = W2 + (size_t)l * 8192;
    unsigned short* dstp = W2t + (size_t)l * 8192;
    for (int i = t; i < 8192; i += 256) {
      int c = i >> 7, k = i & 127;
      dstp[i] = bf16bits(src[k * 64 + c]);
    }
  }
}

// ---------------- lin_in via MFMA: h = bf16(x @ W_in + b_in); f8out = e4m3(relu) --
__global__ __launch_bounds__(256) void k_lin(
    const float* __restrict__ x, const unsigned short* __restrict__ Wint,
    const float* __restrict__ binp, unsigned short* __restrict__ hout,
    unsigned char* __restrict__ f8out) {
  __shared__ __align__(16) unsigned short sW[4096];   // [c=64][8 slots swz]
  __shared__ float sb[64];
  int t = threadIdx.x;
  {
    const uint4* wg = (const uint4*)Wint;
    uint4* sWu = (uint4*)sW;
    for (int g = t; g < 512; g += 256) {
      int c = g >> 3, s = g & 7;
      sWu[c * 8 + (s ^ (c & 7))] = wg[g];
    }
    if (t < 64) sb[t] = binp[t];
  }
  int l = t & 63, w = t >> 6, lm = l & 15, lk = l >> 4;
  int rowl = w * 16 + lm;
  int grow = blockIdx.x * 64 + rowl;
  int growc = min(grow, NN - 1);
  bf16x8 a[2];
#pragma unroll
  for (int kb = 0; kb < 2; kb++) {
    const float* xp = &x[(size_t)growc * 64 + kb * 32 + lk * 8];
    float4 x0 = *(const float4*)xp;
    float4 x1 = *(const float4*)(xp + 4);
    a[kb][0] = (short)bf16bits(x0.x); a[kb][1] = (short)bf16bits(x0.y);
    a[kb][2] = (short)bf16bits(x0.z); a[kb][3] = (short)bf16bits(x0.w);
    a[kb][4] = (short)bf16bits(x1.x); a[kb][5] = (short)bf16bits(x1.y);
    a[kb][6] = (short)bf16bits(x1.z); a[kb][7] = (short)bf16bits(x1.w);
  }
  __syncthreads();
  f32x4 acc[4];
#pragma unroll
  for (int n = 0; n < 4; n++) {
    float bc = sb[n * 16 + lm];
    acc[n] = (f32x4){bc, bc, bc, bc};
  }
  const bf16x8* sWf = (const bf16x8*)sW;
#pragma unroll
  for (int n = 0; n < 4; n++) {
    int c = n * 16 + lm;
    bf16x8 b0 = sWf[c * 8 + ((0 * 4 + lk) ^ (c & 7))];
    bf16x8 b1 = sWf[c * 8 + ((1 * 4 + lk) ^ (c & 7))];
    acc[n] = __builtin_amdgcn_mfma_f32_16x16x32_bf16(a[0], b0, acc[n], 0, 0, 0);
    acc[n] = __builtin_amdgcn_mfma_f32_16x16x32_bf16(a[1], b1, acc[n], 0, 0, 0);
  }
#pragma unroll
  for (int r = 0; r < 4; r++) {
    int grow2 = blockIdx.x * 64 + w * 16 + lk * 4 + r;
    if (grow2 < NN) {
#pragma unroll
      for (int n = 0; n < 4; n++) {
        int c = n * 16 + lm;
        size_t idx = (size_t)grow2 * 64 + c;
        float o = acc[n][r];
        hout[idx] = bf16bits(o);
        f8out[idx] = f8byte(o);
      }
    }
  }
}

// ---------------- fused layer: fp8 gather + MLP (MFMA), degree-sorted nodes -------
// 64 nodes/block (via perm), 4 waves. Degree-uniform waves kill gather divergence.
__global__ __launch_bounds__(256) void k_fused(
    unsigned short* __restrict__ h, const uint2* __restrict__ f8in,
    unsigned char* __restrict__ f8out, const int* __restrict__ perm,
    const int* __restrict__ csr, const int* __restrict__ offs,
    const int* __restrict__ cnt,
    const unsigned short* __restrict__ W1t, const float* __restrict__ b1l,
    const float* __restrict__ gl, const float* __restrict__ btl,
    const unsigned short* __restrict__ W2t, const float* __restrict__ b2l,
    const float* __restrict__ epsl) {
  __shared__ __align__(16) unsigned short sW[8192];   // W1 [c=128][8 swz] then W2 [c=64][16 swz]
  __shared__ __align__(16) unsigned short sRr[8192];  // [r=64][16 slots swz]
  __shared__ float sb1[128], sg[128], sbt[128], sb2[64];

  int t = threadIdx.x;
  int nbase = blockIdx.x * 64;
  int l = t & 63;
  int w = t >> 6;
  int lm = l & 15;
  int lk = l >> 4;

  // stage W1 (swizzled 16B slots) + params
  {
    const uint4* w1g = (const uint4*)W1t;
    uint4* sWu = (uint4*)sW;
    for (int g = t; g < 1024; g += 256) {
      int c = g >> 3, s = g & 7;
      sWu[c * 8 + (s ^ (c & 7))] = w1g[g];
    }
    if (t < 128) { sb1[t] = b1l[t]; sg[t] = gl[t]; sbt[t] = btl[t]; }
    if (t < 64) sb2[t] = b2l[t];
  }
  float epsv = 1.0f + *epsl;

  int rowl = w * 16 + lm;
  int grow = nbase + rowl;
  int growc = min(grow, NN - 1);
  int node = perm[growc];
  int start = offs[node];
  int deg = (grow < NN) ? cnt[node] : 0;

  // issue-early: own-row h (bf16), consumed after the gather loop
  const unsigned short* hp = h + (size_t)node * 64 + lk * 8;
  uint4 hva = *(const uint4*)hp;
  uint4 hvb = *(const uint4*)(hp + 32);

  // ---- gather: 4 threads/node, 16 dims each; 8 edges batched, clamped ----
  float accA[8] = {0.f, 0.f, 0.f, 0.f, 0.f, 0.f, 0.f, 0.f};
  float accB[8] = {0.f, 0.f, 0.f, 0.f, 0.f, 0.f, 0.f, 0.f};
  for (int j0 = 0; j0 < deg; j0 += 8) {
    int idxA = csr[start + j0 + lk];          // over-read <= +7 ints, clamped below
    int idxB = csr[start + j0 + 4 + lk];
    int c8 = deg - j0;
    int ss[8];
#pragma unroll
    for (int jj = 0; jj < 4; jj++) ss[jj] = __shfl(idxA, lm + jj * 16);
#pragma unroll
    for (int jj = 0; jj < 4; jj++) ss[4 + jj] = __shfl(idxB, lm + jj * 16);
    uint2 va[8], vb[8];
#pragma unroll
    for (int jj = 0; jj < 8; jj++) {
      int s = (jj < c8) ? ss[jj] : ss[0];     // clamp: repeat addr = cache hit
      va[jj] = f8in[(size_t)s * 8 + lk];
      vb[jj] = f8in[(size_t)s * 8 + 4 + lk];
    }
#pragma unroll
    for (int jj = 0; jj < 8; jj++) {
      if (jj < c8) {
        f32x2 p;
        p = __builtin_amdgcn_cvt_pk_f32_fp8(va[jj].x, false); accA[0] += p.x; accA[1] += p.y;
        p = __builtin_amdgcn_cvt_pk_f32_fp8(va[jj].x, true);  accA[2] += p.x; accA[3] += p.y;
        p = __builtin_amdgcn_cvt_pk_f32_fp8(va[jj].y, false); accA[4] += p.x; accA[5] += p.y;
        p = __builtin_amdgcn_cvt_pk_f32_fp8(va[jj].y, true);  accA[6] += p.x; accA[7] += p.y;
        p = __builtin_amdgcn_cvt_pk_f32_fp8(vb[jj].x, false); accB[0] += p.x; accB[1] += p.y;
        p = __builtin_amdgcn_cvt_pk_f32_fp8(vb[jj].x, true);  accB[2] += p.x; accB[3] += p.y;
        p = __builtin_amdgcn_cvt_pk_f32_fp8(vb[jj].y, false); accB[4] += p.x; accB[5] += p.y;
        p = __builtin_amdgcn_cvt_pk_f32_fp8(vb[jj].y, true);  accB[6] += p.x; accB[7] += p.y;
      }
    }
  }

  // z = (1+eps)*h + agg -> A-frags
  bf16x8 a1[2];
  {
    float hz[8];
    hz[0] = lo16(hva.x); hz[1] = hi16(hva.x); hz[2] = lo16(hva.y); hz[3] = hi16(hva.y);
    hz[4] = lo16(hva.z); hz[5] = hi16(hva.z); hz[6] = lo16(hva.w); hz[7] = hi16(hva.w);
#pragma unroll
    for (int j = 0; j < 8; j++) a1[0][j] = (short)bf16bits(epsv * hz[j] + accA[j]);
    hz[0] = lo16(hvb.x); hz[1] = hi16(hvb.x); hz[2] = lo16(hvb.y); hz[3] = hi16(hvb.y);
    hz[4] = lo16(hvb.z); hz[5] = hi16(hvb.z); hz[6] = lo16(hvb.w); hz[7] = hi16(hvb.w);
#pragma unroll
    for (int j = 0; j < 8; j++) a1[1][j] = (short)bf16bits(epsv * hz[j] + accB[j]);
  }
  __syncthreads();

  // GEMM1: acc1[n] over 8 col-tiles (sW holds W1)
  f32x4 acc1[8];
#pragma unroll
  for (int n = 0; n < 8; n++) {
    float bc = sb1[n * 16 + lm];
    acc1[n] = (f32x4){bc, bc, bc, bc};
  }
  {
    const bf16x8* sW1f = (const bf16x8*)sW;
#pragma unroll
    for (int n = 0; n < 8; n++) {
      int c = n * 16 + lm;
      bf16x8 b0 = sW1f[c * 8 + ((0 * 4 + lk) ^ (c & 7))];
      bf16x8 b1f = sW1f[c * 8 + ((1 * 4 + lk) ^ (c & 7))];
      acc1[n] = __builtin_amdgcn_mfma_f32_16x16x32_bf16(a1[0], b0, acc1[n], 0, 0, 0);
      acc1[n] = __builtin_amdgcn_mfma_f32_16x16x32_bf16(a1[1], b1f, acc1[n], 0, 0, 0);
    }
  }

  // LayerNorm + relu on D-frags, write swizzled sRr
  float psr[4], pqr[4];
#pragma unroll
  for (int r = 0; r < 4; r++) {
    float s = 0.f, q = 0.f;
#pragma unroll
    for (int n = 0; n < 8; n++) { float v = acc1[n][r]; s += v; q += v * v; }
    psr[r] = s; pqr[r] = q;
  }
#pragma unroll
  for (int m = 1; m <= 8; m <<= 1) {
#pragma unroll
    for (int r = 0; r < 4; r++) {
      psr[r] += __shfl_xor(psr[r], m);
      pqr[r] += __shfl_xor(pqr[r], m);
    }
  }
#pragma unroll
  for (int r = 0; r < 4; r++) {
    float mu = psr[r] * (1.0f / 128.0f);
    float var = pqr[r] * (1.0f / 128.0f) - mu * mu;
    float rs = rsqrtf(var + 1e-5f);
    int rowr = w * 16 + lk * 4 + r;
#pragma unroll
    for (int n = 0; n < 8; n++) {
      int c = n * 16 + lm;
      float v = (acc1[n][r] - mu) * rs * sg[c] + sbt[c];
      v = fmaxf(v, 0.f);
      int slot = (c >> 3) ^ (rowr & 7);
      sRr[rowr * 128 + slot * 8 + (c & 7)] = bf16bits(v);
    }
  }
  __syncthreads();   // sRr ready; all waves past GEMM1 -> sW reusable

  // restage sW = W2 (L2-resident; swizzled 16B slots)
  {
    const uint4* w2g = (const uint4*)W2t;
    uint4* sWu = (uint4*)sW;
    for (int g = t; g < 1024; g += 256) {
      int c = g >> 4, s = g & 15;
      sWu[c * 16 + (s ^ (c & 15))] = w2g[g];
    }
  }
  __syncthreads();   // sW2 ready

  // GEMM2
  f32x4 acc2[4];
#pragma unroll
  for (int n2 = 0; n2 < 4; n2++) {
    float bc = sb2[n2 * 16 + lm];
    acc2[n2] = (f32x4){bc, bc, bc, bc};
  }
  {
    const bf16x8* sRf = (const bf16x8*)sRr;
    const bf16x8* sW2f = (const bf16x8*)sW;
    bf16x8 a2[4];
#pragma unroll
    for (int kb = 0; kb < 4; kb++)
      a2[kb] = sRf[rowl * 16 + ((kb * 4 + lk) ^ (rowl & 7))];
#pragma unroll
    for (int n2 = 0; n2 < 4; n2++) {
      int c = n2 * 16 + lm;
#pragma unroll
      for (int kb = 0; kb < 4; kb++) {
        bf16x8 bfr = sW2f[c * 16 + ((kb * 4 + lk) ^ (c & 15))];
        acc2[n2] = __builtin_amdgcn_mfma_f32_16x16x32_bf16(a2[kb], bfr, acc2[n2], 0, 0, 0);
      }
    }
  }

  // epilogue: h += out + b2 (in place); f8out = e4m3(relu(h_new)) for next layer
#pragma unroll
  for (int r = 0; r < 4; r++) {
    int grow2 = nbase + w * 16 + lk * 4 + r;
    if (grow2 < NN) {
      int node2 = perm[grow2];
#pragma unroll
      for (int n2 = 0; n2 < 4; n2++) {
        int c = n2 * 16 + lm;
        size_t idx = (size_t)node2 * 64 + c;
        float o = b2f(h[idx]) + acc2[n2][r];
        h[idx] = bf16bits(o);
        f8out[idx] = f8byte(o);
      }
    }
  }
}

// ---------------- pooling (bf16 h) ----------------
__global__ void k_pool(const unsigned short* __restrict__ h,
                       const int* __restrict__ batch,
                       float* __restrict__ pooled, int n) {
  int t = threadIdx.x;
  int d = t & 63;
  int w = t >> 6;
  int n0 = blockIdx.x * 256 + w * 64;
  float acc = 0.f;
  int prev = -1;
  for (int i = 0; i < 64; i++) {
    int nn = n0 + i;
    if (nn >= n) break;
    int g = batch[nn];
    if (g != prev) {
      if (prev >= 0) atomicAdd(&pooled[prev * 64 + d], acc);
      prev = g;
      acc = 0.f;
    }
    acc += b2f(h[(size_t)nn * 64 + d]);
  }
  if (prev >= 0) atomicAdd(&pooled[prev * 64 + d], acc);
}

// ---------------- output MLP: one block per graph ----------------
__global__ __launch_bounds__(128) void k_out(
    const float* __restrict__ pooled, const float* __restrict__ Wo1,
    const float* __restrict__ bo1, const float* __restrict__ Wo2,
    const float* __restrict__ bo2, float* __restrict__ out) {
  __shared__ __align__(16) float sP[64];
  __shared__ float sPart[2];
  int g = blockIdx.x;
  int c = threadIdx.x;
  if (c < 64) sP[c] = pooled[g * 64 + c];
  __syncthreads();
  float t1 = bo1[c];
#pragma unroll 8
  for (int k = 0; k < 64; k++) t1 += sP[k] * Wo1[k * 128 + c];
  float v = fmaxf(t1, 0.f) * Wo2[c];
#pragma unroll
  for (int m = 1; m <= 32; m <<= 1) v += __shfl_xor(v, m);
  if ((c & 63) == 0) sPart[c >> 6] = v;
  __syncthreads();
  if (c == 0) out[g] = sPart[0] + sPart[1] + bo2[0];
}

// ---------------- launch ----------------

static inline char* align_up(char* p, size_t a) {
  return (char*)(((uintptr_t)p + a - 1) & ~(uintptr_t)(a - 1));
}

extern "C" void kernel_launch(void* const* d_in, const int* in_sizes, int n_in,
                              void* d_out, int out_size, void* d_ws, size_t ws_size,
                              hipStream_t stream) {
  const float* x    = (const float*)d_in[0];
  const float* W_in = (const float*)d_in[1];
  const float* b_in = (const float*)d_in[2];
  const float* eps  = (const float*)d_in[3];
  const float* W1   = (const float*)d_in[4];
  const float* b1   = (const float*)d_in[5];
  const float* gam  = (const float*)d_in[6];
  const float* bet  = (const float*)d_in[7];
  const float* W2   = (const float*)d_in[8];
  const float* b2   = (const float*)d_in[9];
  const float* Wo1  = (const float*)d_in[10];
  const float* bo1  = (const float*)d_in[11];
  const float* Wo2  = (const float*)d_in[12];
  const float* bo2  = (const float*)d_in[13];
  const int* ei     = (const int*)d_in[14];
  const int* batch  = (const int*)d_in[15];
  float* out = (float*)d_out;

  const int* e_src = ei;
  const int* e_dst = ei + NE;

  char* p = (char*)d_ws;
  unsigned short* h = (unsigned short*)p;   p += (size_t)NN * 64 * 2;   // 12.8 MB
  unsigned char* f8A = (unsigned char*)p;   p += (size_t)NN * 64;       // 6.4 MB
  unsigned char* f8B = (unsigned char*)p;
  unsigned int* tmp = (unsigned int*)p;     // tmp aliases f8B (dead before layer 0)
                                            p += (size_t)NN * 64;       // 6.4 MB
  int* csr = (int*)p;
  int* hist = (int*)p;                      // hist aliases csr (dead before fillB2)
                                            p += (size_t)NE * 4;        // 6.4 MB
  int* offs = (int*)p;                      p += (size_t)NN * 4;
  int* cnt = (int*)p;                       p += (size_t)NN * 4;
  int* perm = (int*)p;                      p += (size_t)NN * 4;
  int* dh = (int*)p;                        p += (size_t)NTOTD * 4;
  int* bsumH = (int*)p;                     p += 1280 * 4;
  int* bsumD = (int*)p;                     p += 128 * 4;
  int* bbase = (int*)p;                     p += (NBUCKET + 1) * 4;
  p = align_up(p, 256);
  float* pooled = (float*)p;                p += (size_t)NGRAPH * 64 * 4;
  p = align_up(p, 256);
  unsigned short* W1t = (unsigned short*)p; p += (size_t)NLAYERS * 8192 * 2;
  unsigned short* W2t = (unsigned short*)p; p += (size_t)NLAYERS * 8192 * 2;
  unsigned short* Wint = (unsigned short*)p; p += 4096 * 2;

  const int SCAN_BLOCKS_H = (NTOT + 255) / 256;      // 599
  const int SCAN_BLOCKS_D = (NTOTD + 255) / 256;     // 98
  const int NODE_BLOCKS = (NN + 63) / 64;            // 1563

  hipMemsetAsync(pooled, 0, (size_t)NGRAPH * 64 * 4, stream);

  // edge CSR
  k_hist<<<NCHUNK, 256, 0, stream>>>(e_dst, hist);
  k_scan1<<<SCAN_BLOCKS_H, 256, 0, stream>>>(hist, hist, bsumH, NTOT);
  k_scan2b<<<1, 256, 0, stream>>>(bsumH, SCAN_BLOCKS_H);
  k_scan3b<<<SCAN_BLOCKS_H, 256, 0, stream>>>(hist, bsumH, bbase, NTOT);
  k_scatter<<<NCHUNK, 256, 0, stream>>>(e_src, e_dst, hist, tmp);
  k_fillB2<<<NBUCKET, 256, 0, stream>>>(tmp, bbase, csr, offs, cnt);

  // degree-sorted node permutation
  k_dhist<<<NCHN, 256, 0, stream>>>(cnt, dh);
  k_scan1<<<SCAN_BLOCKS_D, 256, 0, stream>>>(dh, dh, bsumD, NTOTD);
  k_scan2b<<<1, 256, 0, stream>>>(bsumD, SCAN_BLOCKS_D);
  k_scan3c<<<SCAN_BLOCKS_D, 256, 0, stream>>>(dh, bsumD, NTOTD);
  k_dscatter<<<NCHN, 256, 0, stream>>>(cnt, dh, perm);

  k_prep<<<NLAYERS * 2 + 1, 256, 0, stream>>>(W1, W2, W_in, W1t, W2t, Wint);
  k_lin<<<NODE_BLOCKS, 256, 0, stream>>>(x, Wint, b_in, h, f8A);

  for (int l = 0; l < NLAYERS; l++) {
    const uint2* fin = (const uint2*)((l & 1) ? f8B : f8A);
    unsigned char* fout = (l & 1) ? f8A : f8B;
    k_fused<<<NODE_BLOCKS, 256, 0, stream>>>(h, fin, fout, perm, csr, offs, cnt,
        W1t + (size_t)l * 8192, b1 + (size_t)l * 128,
        gam + (size_t)l * 128, bet + (size_t)l * 128,
        W2t + (size_t)l * 8192, b2 + (size_t)l * 64,
        eps + l);
  }

  k_pool<<<(NN + 255) / 256, 256, 0, stream>>>(h, batch, pooled, NN);
  k_out<<<NGRAPH, 128, 0, stream>>>(pooled, Wo1, bo1, Wo2, bo2, out);
}

// Round 14
// 314.149 us; speedup vs baseline: 1.0642x; 1.0642x over previous
//
#include <hip/hip_runtime.h>
#include <hip/hip_bf16.h>

#define NN 100000
#define NE 1600000
#define DD 64
#define HH 128
#define NLAYERS 4
#define NGRAPH 64
#define NBUCKET 782        // ceil(NN/128) buckets of 128 dst nodes
#define CHUNKSZ 8192
#define NCHUNK 196         // ceil(NE/8192)
#define NTOT (NBUCKET * NCHUNK)   // 153,272

typedef __attribute__((ext_vector_type(8))) short bf16x8;
typedef __attribute__((ext_vector_type(4))) float f32x4;
typedef __attribute__((ext_vector_type(2))) float f32x2;

__device__ inline unsigned short bf16bits(float v) {
  return __bfloat16_as_ushort(__float2bfloat16(v));
}
__device__ inline float lo16(unsigned int u) { return __uint_as_float(u << 16); }
__device__ inline float hi16(unsigned int u) { return __uint_as_float(u & 0xFFFF0000u); }
__device__ inline float b2f(unsigned short u) { return __uint_as_float(((unsigned int)u) << 16); }
__device__ inline unsigned char f8byte(float v) {
  int pk = __builtin_amdgcn_cvt_pk_fp8_f32(fmaxf(v, 0.f), 0.f, 0, false);
  return (unsigned char)(pk & 0xFF);
}

// ---------------- CSR build ----------------

__global__ void k_hist(const int* __restrict__ dst, int* __restrict__ hist) {
  __shared__ int lh[NBUCKET];
  int t = threadIdx.x;
  int blk = blockIdx.x;
  for (int i = t; i < NBUCKET; i += 256) lh[i] = 0;
  __syncthreads();
  int cb = blk * CHUNKSZ;
  int end = min(cb + CHUNKSZ, NE);
  for (int i = cb + t; i < end; i += 256)
    atomicAdd(&lh[dst[i] >> 7], 1);
  __syncthreads();
  for (int i = t; i < NBUCKET; i += 256)
    hist[i * NCHUNK + blk] = lh[i];
}

__global__ void k_scan1(const int* __restrict__ in, int* __restrict__ out,
                        int* __restrict__ bsum, int n) {
  __shared__ int s[256];
  int t = threadIdx.x;
  int i = blockIdx.x * 256 + t;
  int v = (i < n) ? in[i] : 0;
  s[t] = v;
  __syncthreads();
  for (int off = 1; off < 256; off <<= 1) {
    int x = (t >= off) ? s[t - off] : 0;
    __syncthreads();
    s[t] += x;
    __syncthreads();
  }
  if (i < n) out[i] = s[t] - v;
  if (t == 255) bsum[blockIdx.x] = s[255];
}

__global__ void k_scan2b(int* bsum, int nb) {
  __shared__ int s[256];
  int t = threadIdx.x;
  int base = t * 5;
  int v[5];
  int sum = 0;
#pragma unroll
  for (int j = 0; j < 5; j++) {
    int i = base + j;
    v[j] = (i < nb) ? bsum[i] : 0;
    sum += v[j];
  }
  s[t] = sum;
  __syncthreads();
  for (int off = 1; off < 256; off <<= 1) {
    int x = (t >= off) ? s[t - off] : 0;
    __syncthreads();
    s[t] += x;
    __syncthreads();
  }
  int ex = s[t] - sum;
#pragma unroll
  for (int j = 0; j < 5; j++) {
    int i = base + j;
    if (i < nb) { int vv = v[j]; bsum[i] = ex; ex += vv; }
  }
}

// finalize hist offsets + extract per-bucket bases (avoids hist/csr alias race)
__global__ void k_scan3b(int* __restrict__ hist, const int* __restrict__ bsum,
                         int* __restrict__ bbase, int n) {
  int i = blockIdx.x * 256 + threadIdx.x;
  if (i < n) {
    int v = hist[i] + bsum[i >> 8];
    hist[i] = v;
    if (i % NCHUNK == 0) bbase[i / NCHUNK] = v;
  }
}

__global__ void k_scatter(const int* __restrict__ src, const int* __restrict__ dst,
                          const int* __restrict__ hist, unsigned int* __restrict__ tmp) {
  __shared__ int lcur[NBUCKET];
  int t = threadIdx.x;
  int blk = blockIdx.x;
  for (int i = t; i < NBUCKET; i += 256) lcur[i] = hist[i * NCHUNK + blk];
  __syncthreads();
  int cb = blk * CHUNKSZ;
  int end = min(cb + CHUNKSZ, NE);
  for (int i = cb + t; i < end; i += 256) {
    int d = dst[i];
    int pos = atomicAdd(&lcur[d >> 7], 1);
    tmp[pos] = ((unsigned int)(d & 127) << 20) | (unsigned int)src[i];
  }
}

// per-bucket: derive per-node offs/cnt (LDS count+scan), then place edges
__global__ void k_fillB2(const unsigned int* __restrict__ tmp,
                         const int* __restrict__ bbase,
                         int* __restrict__ csr, int* __restrict__ offs,
                         int* __restrict__ cnt) {
  __shared__ int lcnt[128], lex[128], lcur[128];
  int b = blockIdx.x;
  int t = threadIdx.x;
  int base = bbase[b];
  int end = (b == NBUCKET - 1) ? NE : bbase[b + 1];
  if (t < 128) lcnt[t] = 0;
  __syncthreads();
  for (int i = base + t; i < end; i += 256)
    atomicAdd(&lcnt[tmp[i] >> 20], 1);
  __syncthreads();
  int v = (t < 128) ? lcnt[t] : 0;
  if (t < 128) lex[t] = v;
  __syncthreads();
  for (int off = 1; off < 128; off <<= 1) {
    int x = (t >= off && t < 128) ? lex[t - off] : 0;
    __syncthreads();
    if (t < 128) lex[t] += x;
    __syncthreads();
  }
  if (t < 128) {
    int ex = lex[t] - v;
    lcur[t] = ex;
    int node = (b << 7) + t;
    if (node < NN) { offs[node] = base + ex; cnt[node] = v; }
  }
  __syncthreads();
  for (int i = base + t; i < end; i += 256) {
    unsigned int u = tmp[i];
    int dl = u >> 20;
    int pos = atomicAdd(&lcur[dl], 1);
    csr[base + pos] = u & 0xFFFFF;
  }
}

// ---------------- weight prep: bf16 transposed copies ----------------
__global__ void k_prep(const float* __restrict__ W1, const float* __restrict__ W2,
                       const float* __restrict__ W_in,
                       unsigned short* __restrict__ W1t, unsigned short* __restrict__ W2t,
                       unsigned short* __restrict__ Wint) {
  int bidx = blockIdx.x;
  int t = threadIdx.x;
  if (bidx == 2 * NLAYERS) {
    for (int i = t; i < 4096; i += 256) {
      int c = i >> 6, k = i & 63;
      Wint[i] = bf16bits(W_in[k * 64 + c]);
    }
    return;
  }
  int l = bidx >> 1;
  int m = bidx & 1;
  if (m == 0) {
    const float* src = W1 + (size_t)l * 8192;
    unsigned short* dstp = W1t + (size_t)l * 8192;
    for (int i = t; i < 8192; i += 256) {
      int c = i >> 6, k = i & 63;
      dstp[i] = bf16bits(src[k * 128 + c]);
    }
  } else {
    const float* src = W2 + (size_t)l * 8192;
    unsigned short* dstp = W2t + (size_t)l * 8192;
    for (int i = t; i < 8192; i += 256) {
      int c = i >> 7, k = i & 127;
      dstp[i] = bf16bits(src[k * 64 + c]);
    }
  }
}

// ---------------- lin_in via MFMA: h = bf16(x @ W_in + b_in); f8out = e4m3(relu) --
__global__ __launch_bounds__(256) void k_lin(
    const float* __restrict__ x, const unsigned short* __restrict__ Wint,
    const float* __restrict__ binp, unsigned short* __restrict__ hout,
    unsigned char* __restrict__ f8out) {
  __shared__ __align__(16) unsigned short sW[4096];   // [c=64][8 slots swz]
  __shared__ float sb[64];
  int t = threadIdx.x;
  {
    const uint4* wg = (const uint4*)Wint;
    uint4* sWu = (uint4*)sW;
    for (int g = t; g < 512; g += 256) {
      int c = g >> 3, s = g & 7;
      sWu[c * 8 + (s ^ (c & 7))] = wg[g];
    }
    if (t < 64) sb[t] = binp[t];
  }
  int l = t & 63, w = t >> 6, lm = l & 15, lk = l >> 4;
  int rowl = w * 16 + lm;
  int grow = blockIdx.x * 64 + rowl;
  int growc = min(grow, NN - 1);
  bf16x8 a[2];
#pragma unroll
  for (int kb = 0; kb < 2; kb++) {
    const float* xp = &x[(size_t)growc * 64 + kb * 32 + lk * 8];
    float4 x0 = *(const float4*)xp;
    float4 x1 = *(const float4*)(xp + 4);
    a[kb][0] = (short)bf16bits(x0.x); a[kb][1] = (short)bf16bits(x0.y);
    a[kb][2] = (short)bf16bits(x0.z); a[kb][3] = (short)bf16bits(x0.w);
    a[kb][4] = (short)bf16bits(x1.x); a[kb][5] = (short)bf16bits(x1.y);
    a[kb][6] = (short)bf16bits(x1.z); a[kb][7] = (short)bf16bits(x1.w);
  }
  __syncthreads();
  f32x4 acc[4];
#pragma unroll
  for (int n = 0; n < 4; n++) {
    float bc = sb[n * 16 + lm];
    acc[n] = (f32x4){bc, bc, bc, bc};
  }
  const bf16x8* sWf = (const bf16x8*)sW;
#pragma unroll
  for (int n = 0; n < 4; n++) {
    int c = n * 16 + lm;
    bf16x8 b0 = sWf[c * 8 + ((0 * 4 + lk) ^ (c & 7))];
    bf16x8 b1 = sWf[c * 8 + ((1 * 4 + lk) ^ (c & 7))];
    acc[n] = __builtin_amdgcn_mfma_f32_16x16x32_bf16(a[0], b0, acc[n], 0, 0, 0);
    acc[n] = __builtin_amdgcn_mfma_f32_16x16x32_bf16(a[1], b1, acc[n], 0, 0, 0);
  }
#pragma unroll
  for (int r = 0; r < 4; r++) {
    int grow2 = blockIdx.x * 64 + w * 16 + lk * 4 + r;
    if (grow2 < NN) {
#pragma unroll
      for (int n = 0; n < 4; n++) {
        int c = n * 16 + lm;
        size_t idx = (size_t)grow2 * 64 + c;
        float o = acc[n][r];
        hout[idx] = bf16bits(o);
        f8out[idx] = f8byte(o);
      }
    }
  }
}

// ---------------- fused layer: fp8 gather + MLP (MFMA), in-place bf16 h ----------
// 64 nodes/block, 4 waves. Gather pre-relu'd fp8 messages (2x8B per edge-thread,
// HW cvt decode); z = (1+eps)*h + agg -> A-frags; GEMM1 (sW=W1); LN+relu -> sRr;
// restage sW=W2; GEMM2; h += out; f8out = e4m3(relu(h_new)) for next layer.
__global__ __launch_bounds__(256) void k_fused(
    unsigned short* __restrict__ h, const uint2* __restrict__ f8in,
    unsigned char* __restrict__ f8out,
    const int* __restrict__ csr, const int* __restrict__ offs,
    const int* __restrict__ cnt,
    const unsigned short* __restrict__ W1t, const float* __restrict__ b1l,
    const float* __restrict__ gl, const float* __restrict__ btl,
    const unsigned short* __restrict__ W2t, const float* __restrict__ b2l,
    const float* __restrict__ epsl) {
  __shared__ __align__(16) unsigned short sW[8192];   // W1 [c=128][8 swz] then W2 [c=64][16 swz]
  __shared__ __align__(16) unsigned short sRr[8192];  // [r=64][16 slots swz]
  __shared__ float sb1[128], sg[128], sbt[128], sb2[64];

  int t = threadIdx.x;
  int nbase = blockIdx.x * 64;
  int l = t & 63;
  int w = t >> 6;
  int lm = l & 15;
  int lk = l >> 4;

  // stage W1 (swizzled 16B slots) + params
  {
    const uint4* w1g = (const uint4*)W1t;
    uint4* sWu = (uint4*)sW;
    for (int g = t; g < 1024; g += 256) {
      int c = g >> 3, s = g & 7;
      sWu[c * 8 + (s ^ (c & 7))] = w1g[g];
    }
    if (t < 128) { sb1[t] = b1l[t]; sg[t] = gl[t]; sbt[t] = btl[t]; }
    if (t < 64) sb2[t] = b2l[t];
  }
  float epsv = 1.0f + *epsl;

  int rowl = w * 16 + lm;
  int grow = nbase + rowl;
  int growc = min(grow, NN - 1);
  int start = offs[growc];
  int deg = (grow < NN) ? cnt[growc] : 0;

  // issue-early: own-row h (bf16), consumed after the gather loop
  const unsigned short* hp = h + (size_t)growc * 64 + lk * 8;
  uint4 hva = *(const uint4*)hp;
  uint4 hvb = *(const uint4*)(hp + 32);

  // ---- gather: 4 threads/node, 16 dims each; 8 edges batched, clamped ----
  float accA[8] = {0.f, 0.f, 0.f, 0.f, 0.f, 0.f, 0.f, 0.f};
  float accB[8] = {0.f, 0.f, 0.f, 0.f, 0.f, 0.f, 0.f, 0.f};
  for (int j0 = 0; j0 < deg; j0 += 8) {
    int idxA = csr[start + j0 + lk];          // over-read <= +7 ints, clamped below
    int idxB = csr[start + j0 + 4 + lk];
    int c8 = deg - j0;
    int ss[8];
#pragma unroll
    for (int jj = 0; jj < 4; jj++) ss[jj] = __shfl(idxA, lm + jj * 16);
#pragma unroll
    for (int jj = 0; jj < 4; jj++) ss[4 + jj] = __shfl(idxB, lm + jj * 16);
    uint2 va[8], vb[8];
#pragma unroll
    for (int jj = 0; jj < 8; jj++) {
      int s = (jj < c8) ? ss[jj] : ss[0];     // clamp: repeat addr = cache hit
      va[jj] = f8in[(size_t)s * 8 + lk];
      vb[jj] = f8in[(size_t)s * 8 + 4 + lk];
    }
#pragma unroll
    for (int jj = 0; jj < 8; jj++) {
      if (jj < c8) {
        f32x2 p;
        p = __builtin_amdgcn_cvt_pk_f32_fp8(va[jj].x, false); accA[0] += p.x; accA[1] += p.y;
        p = __builtin_amdgcn_cvt_pk_f32_fp8(va[jj].x, true);  accA[2] += p.x; accA[3] += p.y;
        p = __builtin_amdgcn_cvt_pk_f32_fp8(va[jj].y, false); accA[4] += p.x; accA[5] += p.y;
        p = __builtin_amdgcn_cvt_pk_f32_fp8(va[jj].y, true);  accA[6] += p.x; accA[7] += p.y;
        p = __builtin_amdgcn_cvt_pk_f32_fp8(vb[jj].x, false); accB[0] += p.x; accB[1] += p.y;
        p = __builtin_amdgcn_cvt_pk_f32_fp8(vb[jj].x, true);  accB[2] += p.x; accB[3] += p.y;
        p = __builtin_amdgcn_cvt_pk_f32_fp8(vb[jj].y, false); accB[4] += p.x; accB[5] += p.y;
        p = __builtin_amdgcn_cvt_pk_f32_fp8(vb[jj].y, true);  accB[6] += p.x; accB[7] += p.y;
      }
    }
  }

  // z = (1+eps)*h + agg -> A-frags
  bf16x8 a1[2];
  {
    float hz[8];
    hz[0] = lo16(hva.x); hz[1] = hi16(hva.x); hz[2] = lo16(hva.y); hz[3] = hi16(hva.y);
    hz[4] = lo16(hva.z); hz[5] = hi16(hva.z); hz[6] = lo16(hva.w); hz[7] = hi16(hva.w);
#pragma unroll
    for (int j = 0; j < 8; j++) a1[0][j] = (short)bf16bits(epsv * hz[j] + accA[j]);
    hz[0] = lo16(hvb.x); hz[1] = hi16(hvb.x); hz[2] = lo16(hvb.y); hz[3] = hi16(hvb.y);
    hz[4] = lo16(hvb.z); hz[5] = hi16(hvb.z); hz[6] = lo16(hvb.w); hz[7] = hi16(hvb.w);
#pragma unroll
    for (int j = 0; j < 8; j++) a1[1][j] = (short)bf16bits(epsv * hz[j] + accB[j]);
  }
  __syncthreads();

  // GEMM1: acc1[n] over 8 col-tiles (sW holds W1)
  f32x4 acc1[8];
#pragma unroll
  for (int n = 0; n < 8; n++) {
    float bc = sb1[n * 16 + lm];
    acc1[n] = (f32x4){bc, bc, bc, bc};
  }
  {
    const bf16x8* sW1f = (const bf16x8*)sW;
#pragma unroll
    for (int n = 0; n < 8; n++) {
      int c = n * 16 + lm;
      bf16x8 b0 = sW1f[c * 8 + ((0 * 4 + lk) ^ (c & 7))];
      bf16x8 b1f = sW1f[c * 8 + ((1 * 4 + lk) ^ (c & 7))];
      acc1[n] = __builtin_amdgcn_mfma_f32_16x16x32_bf16(a1[0], b0, acc1[n], 0, 0, 0);
      acc1[n] = __builtin_amdgcn_mfma_f32_16x16x32_bf16(a1[1], b1f, acc1[n], 0, 0, 0);
    }
  }

  // LayerNorm + relu on D-frags, write swizzled sRr
  float psr[4], pqr[4];
#pragma unroll
  for (int r = 0; r < 4; r++) {
    float s = 0.f, q = 0.f;
#pragma unroll
    for (int n = 0; n < 8; n++) { float v = acc1[n][r]; s += v; q += v * v; }
    psr[r] = s; pqr[r] = q;
  }
#pragma unroll
  for (int m = 1; m <= 8; m <<= 1) {
#pragma unroll
    for (int r = 0; r < 4; r++) {
      psr[r] += __shfl_xor(psr[r], m);
      pqr[r] += __shfl_xor(pqr[r], m);
    }
  }
#pragma unroll
  for (int r = 0; r < 4; r++) {
    float mu = psr[r] * (1.0f / 128.0f);
    float var = pqr[r] * (1.0f / 128.0f) - mu * mu;
    float rs = rsqrtf(var + 1e-5f);
    int rowr = w * 16 + lk * 4 + r;
#pragma unroll
    for (int n = 0; n < 8; n++) {
      int c = n * 16 + lm;
      float v = (acc1[n][r] - mu) * rs * sg[c] + sbt[c];
      v = fmaxf(v, 0.f);
      int slot = (c >> 3) ^ (rowr & 7);
      sRr[rowr * 128 + slot * 8 + (c & 7)] = bf16bits(v);
    }
  }
  __syncthreads();   // sRr ready; all waves past GEMM1 -> sW reusable

  // restage sW = W2 (L2-resident; swizzled 16B slots)
  {
    const uint4* w2g = (const uint4*)W2t;
    uint4* sWu = (uint4*)sW;
    for (int g = t; g < 1024; g += 256) {
      int c = g >> 4, s = g & 15;
      sWu[c * 16 + (s ^ (c & 15))] = w2g[g];
    }
  }
  __syncthreads();   // sW2 ready

  // GEMM2
  f32x4 acc2[4];
#pragma unroll
  for (int n2 = 0; n2 < 4; n2++) {
    float bc = sb2[n2 * 16 + lm];
    acc2[n2] = (f32x4){bc, bc, bc, bc};
  }
  {
    const bf16x8* sRf = (const bf16x8*)sRr;
    const bf16x8* sW2f = (const bf16x8*)sW;
    bf16x8 a2[4];
#pragma unroll
    for (int kb = 0; kb < 4; kb++)
      a2[kb] = sRf[rowl * 16 + ((kb * 4 + lk) ^ (rowl & 7))];
#pragma unroll
    for (int n2 = 0; n2 < 4; n2++) {
      int c = n2 * 16 + lm;
#pragma unroll
      for (int kb = 0; kb < 4; kb++) {
        bf16x8 bfr = sW2f[c * 16 + ((kb * 4 + lk) ^ (c & 15))];
        acc2[n2] = __builtin_amdgcn_mfma_f32_16x16x32_bf16(a2[kb], bfr, acc2[n2], 0, 0, 0);
      }
    }
  }

  // epilogue: h += out + b2 (in place); f8out = e4m3(relu(h_new)) for next layer
#pragma unroll
  for (int r = 0; r < 4; r++) {
    int grow2 = nbase + w * 16 + lk * 4 + r;
    if (grow2 < NN) {
#pragma unroll
      for (int n2 = 0; n2 < 4; n2++) {
        int c = n2 * 16 + lm;
        size_t idx = (size_t)grow2 * 64 + c;
        float o = b2f(h[idx]) + acc2[n2][r];
        h[idx] = bf16bits(o);
        f8out[idx] = f8byte(o);
      }
    }
  }
}

// ---------------- pooling (bf16 h) ----------------
__global__ void k_pool(const unsigned short* __restrict__ h,
                       const int* __restrict__ batch,
                       float* __restrict__ pooled, int n) {
  int t = threadIdx.x;
  int d = t & 63;
  int w = t >> 6;
  int n0 = blockIdx.x * 256 + w * 64;
  float acc = 0.f;
  int prev = -1;
  for (int i = 0; i < 64; i++) {
    int nn = n0 + i;
    if (nn >= n) break;
    int g = batch[nn];
    if (g != prev) {
      if (prev >= 0) atomicAdd(&pooled[prev * 64 + d], acc);
      prev = g;
      acc = 0.f;
    }
    acc += b2f(h[(size_t)nn * 64 + d]);
  }
  if (prev >= 0) atomicAdd(&pooled[prev * 64 + d], acc);
}

// ---------------- output MLP: one block per graph ----------------
__global__ __launch_bounds__(128) void k_out(
    const float* __restrict__ pooled, const float* __restrict__ Wo1,
    const float* __restrict__ bo1, const float* __restrict__ Wo2,
    const float* __restrict__ bo2, float* __restrict__ out) {
  __shared__ __align__(16) float sP[64];
  __shared__ float sPart[2];
  int g = blockIdx.x;
  int c = threadIdx.x;
  if (c < 64) sP[c] = pooled[g * 64 + c];
  __syncthreads();
  float t1 = bo1[c];
#pragma unroll 8
  for (int k = 0; k < 64; k++) t1 += sP[k] * Wo1[k * 128 + c];
  float v = fmaxf(t1, 0.f) * Wo2[c];
#pragma unroll
  for (int m = 1; m <= 32; m <<= 1) v += __shfl_xor(v, m);
  if ((c & 63) == 0) sPart[c >> 6] = v;
  __syncthreads();
  if (c == 0) out[g] = sPart[0] + sPart[1] + bo2[0];
}

// ---------------- launch ----------------

static inline char* align_up(char* p, size_t a) {
  return (char*)(((uintptr_t)p + a - 1) & ~(uintptr_t)(a - 1));
}

extern "C" void kernel_launch(void* const* d_in, const int* in_sizes, int n_in,
                              void* d_out, int out_size, void* d_ws, size_t ws_size,
                              hipStream_t stream) {
  const float* x    = (const float*)d_in[0];
  const float* W_in = (const float*)d_in[1];
  const float* b_in = (const float*)d_in[2];
  const float* eps  = (const float*)d_in[3];
  const float* W1   = (const float*)d_in[4];
  const float* b1   = (const float*)d_in[5];
  const float* gam  = (const float*)d_in[6];
  const float* bet  = (const float*)d_in[7];
  const float* W2   = (const float*)d_in[8];
  const float* b2   = (const float*)d_in[9];
  const float* Wo1  = (const float*)d_in[10];
  const float* bo1  = (const float*)d_in[11];
  const float* Wo2  = (const float*)d_in[12];
  const float* bo2  = (const float*)d_in[13];
  const int* ei     = (const int*)d_in[14];
  const int* batch  = (const int*)d_in[15];
  float* out = (float*)d_out;

  const int* e_src = ei;
  const int* e_dst = ei + NE;

  char* p = (char*)d_ws;
  unsigned short* h = (unsigned short*)p;   p += (size_t)NN * 64 * 2;   // 12.8 MB
  unsigned char* f8A = (unsigned char*)p;   p += (size_t)NN * 64;       // 6.4 MB
  unsigned char* f8B = (unsigned char*)p;
  unsigned int* tmp = (unsigned int*)p;     // tmp aliases f8B (dead before layer 0)
                                            p += (size_t)NN * 64;       // 6.4 MB
  int* csr = (int*)p;
  int* hist = (int*)p;                      // hist aliases csr (dead before fillB2)
                                            p += (size_t)NE * 4;        // 6.4 MB
  int* offs = (int*)p;                      p += (size_t)NN * 4;
  int* cnt = (int*)p;                       p += (size_t)NN * 4;
  int* bsumH = (int*)p;                     p += 1280 * 4;
  int* bbase = (int*)p;                     p += (NBUCKET + 1) * 4;
  p = align_up(p, 256);
  float* pooled = (float*)p;                p += (size_t)NGRAPH * 64 * 4;
  p = align_up(p, 256);
  unsigned short* W1t = (unsigned short*)p; p += (size_t)NLAYERS * 8192 * 2;
  unsigned short* W2t = (unsigned short*)p; p += (size_t)NLAYERS * 8192 * 2;
  unsigned short* Wint = (unsigned short*)p; p += 4096 * 2;

  const int SCAN_BLOCKS_H = (NTOT + 255) / 256;      // 599
  const int NODE_BLOCKS = (NN + 63) / 64;            // 1563

  hipMemsetAsync(pooled, 0, (size_t)NGRAPH * 64 * 4, stream);

  k_hist<<<NCHUNK, 256, 0, stream>>>(e_dst, hist);
  k_scan1<<<SCAN_BLOCKS_H, 256, 0, stream>>>(hist, hist, bsumH, NTOT);
  k_scan2b<<<1, 256, 0, stream>>>(bsumH, SCAN_BLOCKS_H);
  k_scan3b<<<SCAN_BLOCKS_H, 256, 0, stream>>>(hist, bsumH, bbase, NTOT);
  k_scatter<<<NCHUNK, 256, 0, stream>>>(e_src, e_dst, hist, tmp);
  k_fillB2<<<NBUCKET, 256, 0, stream>>>(tmp, bbase, csr, offs, cnt);

  k_prep<<<NLAYERS * 2 + 1, 256, 0, stream>>>(W1, W2, W_in, W1t, W2t, Wint);
  k_lin<<<NODE_BLOCKS, 256, 0, stream>>>(x, Wint, b_in, h, f8A);

  for (int l = 0; l < NLAYERS; l++) {
    const uint2* fin = (const uint2*)((l & 1) ? f8B : f8A);
    unsigned char* fout = (l & 1) ? f8A : f8B;
    k_fused<<<NODE_BLOCKS, 256, 0, stream>>>(h, fin, fout, csr, offs, cnt,
        W1t + (size_t)l * 8192, b1 + (size_t)l * 128,
        gam + (size_t)l * 128, bet + (size_t)l * 128,
        W2t + (size_t)l * 8192, b2 + (size_t)l * 64,
        eps + l);
  }

  k_pool<<<(NN + 255) / 256, 256, 0, stream>>>(h, batch, pooled, NN);
  k_out<<<NGRAPH, 128, 0, stream>>>(pooled, Wo1, bo1, Wo2, bo2, out);
}